// Round 18
// baseline (795.016 us; speedup 1.0000x reference)
//
#include <hip/hip_runtime.h>
#include <math.h>

#define NB 16
#define NLOC 21824
#define NCLS 80
#define NLVL 5
#define MM 5000
#define MROWS 5056      // 79 groups x 64 rows (group == diagonal word)
#define GRPS 79
#define SLOTB 40960     // bytes per slot = 64 rows * 640B
#define CAP 4096
#define EPB 1745920     // entries per batch = NLOC*NCLS
#define NCHUNK 16       // fused-pass chunks per batch (level-aligned)
#define NBUCK 16384     // vb>>16 buckets (vb < 2^30)
#define CAND_PB 436480  // candidate keys per batch (25% of each level's entries)
#define WBUF 256        // keys per wave-private staging buffer
#define BSLACK 4        // cutoff slack buckets (fast-key hist error <=1-2; 2x margin)

__device__ __forceinline__ int level_of(int r) {
    return (r < 1310720) ? 0 : (r < 1638400) ? 1 : (r < 1720320) ? 2 : (r < 1740800) ? 3 : 4;
}
__device__ __constant__ int d_estart[5] = {0, 1310720, 1638400, 1720320, 1740800};
__device__ __constant__ int d_lstart[5] = {0, 16384, 20480, 21504, 21760};
// candidate-list layout (keys): per-level capacity = entries/4, per-batch offsets
__device__ __constant__ int d_ccap[5] = {327680, 81920, 20480, 5120, 1280};
__device__ __constant__ int d_coff[5] = {0, 327680, 409600, 430080, 435200};
// k_mask block map: per-batch 110 blocks; start offset per row-chunk rc (cg_min = rc/2)
__device__ __constant__ int d_mstart[20] = {0,10,20,29,38,46,54,61,68,74,80,85,90,94,98,101,104,106,108,109};
// fused-pass chunk tables (entry offsets within batch; each chunk inside one level)
__device__ __constant__ int d_cstart[NCHUNK] = {0,131072,262144,393216,524288,655360,786432,917504,
                                                1048576,1179648,1310720,1441792,1572864,1638400,1720320,1740800};
__device__ __constant__ int d_csize[NCHUNK]  = {131072,131072,131072,131072,131072,131072,131072,131072,
                                                131072,131072,131072,131072,65536,81920,20480,5120};

// ---------------- Kernel P: centerness sigmoid table (bit-identical to reference) --------
__global__ void k_ctr(const float* __restrict__ ctr, float* __restrict__ sigc) {
    int i = blockIdx.x * 256 + threadIdx.x;
    if (i < NB * NLOC) {
        float c = ctr[i];
        sigc[i] = (float)(1.0 / (1.0 + exp(-(double)c)));
    }
}

// ---------------- Kernel A''': ONE cls pass -> FAST candidate keys ----------------
// r18: fast fp32 sigmoid for candidate keys (removes ~4M double-exp chains). Gate
// widened to 0.049999f so every exact-passing entry (exact sf>0.05) is retained.
// Exact keys are recomputed in k_filter for the ~1.5K/g survivors (r14-proven
// slack/superset pattern). Wave-private LDS buffers, one atomic per 256-key flush.
__global__ __launch_bounds__(1024) void k_fused(const float* __restrict__ cls,
                                                const float* __restrict__ sigc,
                                                unsigned int* __restrict__ candCnt,
                                                unsigned long long* __restrict__ cand,
                                                unsigned int* __restrict__ ovf) {
    __shared__ unsigned long long wbuf[16 * WBUF];   // 32768 B
    int blk = blockIdx.x;
    int b = blk >> 4;
    int c = blk & 15;
    int tid = threadIdx.x;
    int lane = tid & 63;
    int wslot = (tid >> 6) * WBUF;
    int n4 = d_csize[c] >> 2;
    int r0base = d_cstart[c];
    int l = level_of(r0base);          // chunk is level-uniform
    int g = b * 5 + l;
    unsigned int capg = (unsigned int)d_ccap[l];
    unsigned long long* cg = cand + (size_t)b * CAND_PB + d_coff[l];
    const float4* src = (const float4*)(cls + ((long long)b * EPB + r0base));

    unsigned int wbase = 0;   // wave-uniform count of keys staged in this wave's buffer

    auto flushw = [&]() {     // wave-converged only
        if (wbase > 0) {
            unsigned int gbase = 0;
            if (lane == 0) gbase = atomicAdd(&candCnt[g], wbase);
            gbase = (unsigned int)__shfl((int)gbase, 0, 64);
            for (unsigned int k = (unsigned int)lane; k < wbase; k += 64) {
                unsigned int my = gbase + k;
                if (my < capg) cg[my] = wbuf[wslot + k];
                else ovf[g] = 1u;
            }
            wbase = 0;
        }
    };

    for (int i = tid; i < n4; i += 1024) {
        float4 x4 = src[i];
        int r0 = r0base + i * 4;
        bool any = !(x4.x <= -2.945f && x4.y <= -2.945f && x4.z <= -2.945f && x4.w <= -2.945f);
        float cf = 0.f;
        if (any) cf = sigc[b * NLOC + r0 / 80];   // 4 | 80: all 4 share the location
        float xs[4] = {x4.x, x4.y, x4.z, x4.w};
#pragma unroll
        for (int j = 0; j < 4; ++j) {
            float x = xs[j];
            bool pass = false;
            unsigned long long key = 0ULL;
            if (x > -2.945f) {                         // exact sf there <=0.049968 -> fast fails too
                float sf = 1.0f / (1.0f + __expf(-x)); // FAST (key refined in k_filter)
                if (sf > 0.049999f) {                  // widened gate: superset of exact
                    float val = sf * cf;
                    unsigned int vb = __float_as_uint(val);
                    unsigned int idx = (unsigned int)(r0 + j - d_estart[l]);
                    key = ((unsigned long long)vb << 21) | (unsigned long long)(0x1FFFFFu - idx);
                    pass = true;
                }
            }
            unsigned long long mk = __ballot(pass);
            unsigned int wcnt = (unsigned int)__popcll(mk);
            if (wbase + wcnt > WBUF) flushw();
            if (pass) {
                unsigned int pos = wbase + (unsigned int)__popcll(mk & ((1ULL << lane) - 1ULL));
                wbuf[wslot + pos] = key;
            }
            wbase += wcnt;
        }
    }
    flushw();
}

// ---------------- Kernel B'': cutoff bucket from fast keys, slack applied --------
__global__ __launch_bounds__(1024) void k_cutoff2(const unsigned int* __restrict__ candCnt,
                                                  const unsigned long long* __restrict__ cand,
                                                  const unsigned int* __restrict__ ovf,
                                                  const float* __restrict__ cls,
                                                  const float* __restrict__ sigc,
                                                  unsigned int* __restrict__ bcut) {
    __shared__ unsigned int lh[NBUCK];   // 65536 B
    __shared__ unsigned int ssum[1024];
    int g = blockIdx.x;  // 0..79
    int b = g / 5, l = g % 5;
    int tid = threadIdx.x;
    for (int i = tid; i < NBUCK; i += 1024) lh[i] = 0;
    __syncthreads();
    bool fastpath = !ovf[g];
    if (fastpath) {
        int n = min((int)candCnt[g], d_ccap[l]);
        const unsigned long long* cg = cand + (size_t)b * CAND_PB + d_coff[l];
        for (int i = tid; i < n; i += 1024) {
            unsigned int vb = (unsigned int)(cg[i] >> 21);
            atomicAdd(&lh[vb >> 16], 1u);
        }
    } else {
        // exact fallback: rescan this level's cls region (never expected)
        int start = d_estart[l];
        int sz4 = (((l < 4) ? d_estart[l + 1] : EPB) - start) >> 2;
        const float4* src = (const float4*)(cls + ((long long)b * EPB + start));
        for (int i = tid; i < sz4; i += 1024) {
            float4 x4 = src[i];
            if (x4.x <= -2.945f && x4.y <= -2.945f && x4.z <= -2.945f && x4.w <= -2.945f)
                continue;
            int r0 = start + i * 4;
            float cf = sigc[b * NLOC + r0 / 80];
            float xs[4] = {x4.x, x4.y, x4.z, x4.w};
#pragma unroll
            for (int j = 0; j < 4; ++j) {
                float x = xs[j];
                if (x <= -2.945f) continue;
                double sd = 1.0 / (1.0 + exp(-(double)x));
                float sf = (float)sd;
                if (!(sf > 0.05f)) continue;
                unsigned int vb = __float_as_uint(sf * cf);
                atomicAdd(&lh[vb >> 16], 1u);
            }
        }
    }
    __syncthreads();
    unsigned int s2 = 0;
    for (int k = 0; k < 16; ++k) s2 += lh[tid * 16 + k];
    ssum[tid] = s2;
    __syncthreads();
    if (tid == 0) {
        unsigned int cum = 0;
        int bucket = 0;
        int ch = 1023;
        for (; ch >= 0; ch--) {
            if (cum + ssum[ch] >= 1000u) break;
            cum += ssum[ch];
        }
        if (ch >= 0) {
            int bi = ch * 16 + 15;
            for (; bi > ch * 16; bi--) {
                unsigned int cc = lh[bi];
                if (cum + cc >= 1000u) break;
                cum += cc;
            }
            bucket = bi;
        }
        if (fastpath) bucket = (bucket > BSLACK) ? bucket - BSLACK : 0;  // slack: fast keys
        bcut[g] = (unsigned int)bucket;
    }
}

// ---------------- Kernel C'': filter fast keys; EXACT key recompute for survivors -------
__global__ __launch_bounds__(256) void k_filter(const unsigned int* __restrict__ candCnt,
                                                const unsigned long long* __restrict__ cand,
                                                const unsigned int* __restrict__ ovf,
                                                const unsigned int* __restrict__ bcut,
                                                const float* __restrict__ cls,
                                                const float* __restrict__ sigc,
                                                unsigned int* __restrict__ cnt,
                                                unsigned long long* __restrict__ compact) {
    int id = blockIdx.x;          // 80 g x 16 sub
    int g = id >> 4;
    int sub = id & 15;
    int b = g / 5, l = g % 5;
    int tid = threadIdx.x;
    unsigned int bc = bcut[g];
    if (!ovf[g]) {
        int n = min((int)candCnt[g], d_ccap[l]);
        const unsigned long long* cg = cand + (size_t)b * CAND_PB + d_coff[l];
        int start = d_estart[l];
        for (int i = sub * 256 + tid; i < n; i += 4096) {
            unsigned long long key = cg[i];
            unsigned int vb = (unsigned int)(key >> 21);
            if ((vb >> 16) >= bc) {
                // survivor: recompute EXACT key (bit-identical to reference math)
                unsigned int idx = 0x1FFFFFu - (unsigned int)(key & 0x1FFFFFu);
                int e = start + (int)idx;
                float x = cls[(long long)b * EPB + e];
                float cf = sigc[b * NLOC + e / 80];
                double sd = 1.0 / (1.0 + exp(-(double)x));
                float sf = (float)sd;
                if (sf > 0.05f) {
                    unsigned int vbe = __float_as_uint(sf * cf);
                    unsigned int pos = atomicAdd(&cnt[g], 1u);
                    if (pos < CAP)
                        compact[(long long)g * CAP + pos] =
                            ((unsigned long long)vbe << 21) | (unsigned long long)(0x1FFFFFu - idx);
                }
            }
        }
    } else {
        // exact fallback: rescan level (never expected)
        int start = d_estart[l];
        int sz4 = (((l < 4) ? d_estart[l + 1] : EPB) - start) >> 2;
        const float4* src = (const float4*)(cls + ((long long)b * EPB + start));
        for (int i = sub * 256 + tid; i < sz4; i += 4096) {
            float4 x4 = src[i];
            if (x4.x <= -2.945f && x4.y <= -2.945f && x4.z <= -2.945f && x4.w <= -2.945f)
                continue;
            int r0 = start + i * 4;
            float cf = sigc[b * NLOC + r0 / 80];
            float xs[4] = {x4.x, x4.y, x4.z, x4.w};
#pragma unroll
            for (int j = 0; j < 4; ++j) {
                float x = xs[j];
                if (x <= -2.945f) continue;
                double sd = 1.0 / (1.0 + exp(-(double)x));
                float sf = (float)sd;
                if (!(sf > 0.05f)) continue;
                unsigned int vb = __float_as_uint(sf * cf);
                if ((vb >> 16) >= bc) {
                    unsigned int idx = (unsigned int)(r0 + j - d_estart[l]);
                    unsigned int pos = atomicAdd(&cnt[g], 1u);
                    if (pos < CAP)
                        compact[(long long)g * CAP + pos] =
                            ((unsigned long long)vb << 21) | (unsigned long long)(0x1FFFFFu - idx);
                }
            }
        }
    }
}

// ---------------- Kernel D: per-(b,l) bitonic sort + build global keys ----------------
__global__ void k_select(const unsigned int* __restrict__ cnt,
                         const unsigned long long* __restrict__ compact,
                         unsigned long long* __restrict__ pool) {
    __shared__ unsigned long long sk[CAP];
    int g = blockIdx.x;
    int b = g / 5, l = g % 5;
    int count = min((int)cnt[g], CAP);
    for (int p = threadIdx.x; p < CAP; p += blockDim.x)
        sk[p] = (p < count) ? compact[(long long)g * CAP + p] : 0ULL;
    __syncthreads();
    for (int k = 2; k <= CAP; k <<= 1) {
        for (int j = k >> 1; j > 0; j >>= 1) {
            for (int i = threadIdx.x; i < CAP; i += blockDim.x) {
                int ixj = i ^ j;
                if (ixj > i) {
                    unsigned long long a = sk[i], bb = sk[ixj];
                    bool desc = ((i & k) == 0);
                    if (desc ? (a < bb) : (a > bb)) { sk[i] = bb; sk[ixj] = a; }
                }
            }
            __syncthreads();
        }
    }
    int ksel = min(1000, count);
    for (int r = threadIdx.x; r < 1000; r += blockDim.x) {
        unsigned long long gk = 0ULL;
        if (r < ksel) {
            unsigned long long key = sk[r];
            unsigned int vb = (unsigned int)(key >> 21);
            unsigned int idx = 0x1FFFFFu - (unsigned int)(key & 0x1FFFFFu);
            float val = __uint_as_float(vb);
            float sc = sqrtf(val);
            unsigned long long sb = (unsigned long long)__float_as_uint(sc);
            gk = (sb << 34) | ((unsigned long long)(7 - l) << 31) |
                 ((unsigned long long)(1023 - r) << 21) | (unsigned long long)idx;
        }
        pool[(long long)b * MM + l * 1000 + r] = gk;
    }
}

// ---------------- Kernel E': 5-way merge by exact rank ----------------
__global__ __launch_bounds__(1024) void k_merge(const unsigned long long* __restrict__ pool,
                                                const unsigned int* __restrict__ cnt,
                                                unsigned long long* __restrict__ sorted) {
    __shared__ unsigned long long sp[MM];
    __shared__ int s_nz[5];
    int b = blockIdx.x, t = threadIdx.x;
    for (int p = t; p < MM; p += 1024) sp[p] = pool[(long long)b * MM + p];
    if (t < 5) s_nz[t] = (int)min(cnt[b * 5 + t], 1000u);
    __syncthreads();
    int nzTot = s_nz[0] + s_nz[1] + s_nz[2] + s_nz[3] + s_nz[4];
    for (int p = t; p < MM; p += 1024) {
        int l = p / 1000, r = p - l * 1000;
        unsigned long long K = sp[p];
        int rank;
        if (K) {
            rank = r;
#pragma unroll
            for (int l2 = 0; l2 < 5; ++l2) {
                if (l2 == l) continue;
                const unsigned long long* L = sp + l2 * 1000;
                int lo = 0, hi = s_nz[l2];
                while (lo < hi) {
                    int mid = (lo + hi) >> 1;
                    if (L[mid] > K) lo = mid + 1; else hi = mid;
                }
                rank += lo;
            }
        } else {
            int zi = 0;
#pragma unroll
            for (int l2 = 0; l2 < 5; ++l2) if (l2 < l) zi += 1000 - s_nz[l2];
            zi += r - s_nz[l];
            rank = nzTot + zi;
        }
        sorted[(long long)b * MM + rank] = K;
    }
}

// ---------------- Kernel F: decode boxes/scores/classes ----------------
__global__ void k_decode(const unsigned long long* __restrict__ sorted,
                         const float* __restrict__ reg, const float* __restrict__ locs,
                         float4* __restrict__ boxesWS, float* __restrict__ scoresWS,
                         float* __restrict__ clsWS, unsigned int* __restrict__ validWS) {
    int g = blockIdx.x * blockDim.x + threadIdx.x;
    if (g >= NB * MM) return;
    int b = g / MM;
    unsigned long long gk = sorted[g];
    float4 bx = make_float4(0.f, 0.f, 0.f, 0.f);
    float sc = 0.f, cf = 0.f;
    unsigned int v = 0;
    if (gk) {
        sc = __uint_as_float((unsigned int)(gk >> 34));
        int l = 7 - (int)((gk >> 31) & 7);
        int idx = (int)(gk & 0x1FFFFF);
        int loc = idx / 80;
        int c = idx - loc * 80;
        int gl = d_lstart[l] + loc;
        float lx = locs[gl * 2], ly = locs[gl * 2 + 1];
        const float* r4 = reg + ((long long)b * NLOC + gl) * 4;
        float x1 = fminf(fmaxf(lx - r4[0], 0.f), 1024.f);
        float y1 = fminf(fmaxf(ly - r4[1], 0.f), 1024.f);
        float x2 = fminf(fmaxf(lx + r4[2], 0.f), 1024.f);
        float y2 = fminf(fmaxf(ly + r4[3], 0.f), 1024.f);
        bx = make_float4(x1, y1, x2, y2);
        cf = (float)(c + 1);
        v = 1;
    }
    boxesWS[g] = bx;
    scoresWS[g] = sc;
    clsWS[g] = cf;
    validWS[g] = v;
}

// ---------------- Kernel M: pairwise suppression bitmask (tiled) ----------------
__global__ __launch_bounds__(256) void k_mask(const float4* __restrict__ boxesWS,
                                              unsigned long long* __restrict__ mask) {
    __shared__ float4 cb[512];
    __shared__ float ca[512];
    int id = blockIdx.x;
    int b = id / 110;
    int q = id - b * 110;
    int rc = 19;
    for (int r = 1; r < 20; ++r) if (q < d_mstart[r]) { rc = r - 1; break; }
    int cg = rc / 2 + (q - d_mstart[rc]);
    int t = threadIdx.x;
    int i = rc * 256 + t;
    int c0 = cg * 512;
    for (int c = t; c < 512; c += 256) {
        int j = c0 + c;
        float4 v = (j < MM) ? boxesWS[b * MM + j] : make_float4(0.f, 0.f, 0.f, 0.f);
        cb[c] = v;
        ca[c] = (v.z - v.x) * (v.w - v.y);
    }
    __syncthreads();
    if (i >= MM) return;
    float4 hb = boxesWS[b * MM + i];
    float hA = (hb.z - hb.x) * (hb.w - hb.y);
    int iw0 = i >> 6;
    int cg8 = cg * 8;
    unsigned long long wbuf[8];
#pragma unroll
    for (int k = 0; k < 8; ++k) {
        int w = cg8 + k;
        unsigned long long m = 0ULL;
        if (w >= iw0) {
            int cbase = w * 64 - c0;
            for (int jj = 0; jj < 64; ++jj) {
                float4 cbj = cb[cbase + jj];
                float xi1 = fmaxf(hb.x, cbj.x);
                float yi1 = fmaxf(hb.y, cbj.y);
                float xi2 = fminf(hb.z, cbj.z);
                float yi2 = fminf(hb.w, cbj.w);
                float inter = fmaxf(xi2 - xi1, 0.f) * fmaxf(yi2 - yi1, 0.f);
                float iou = inter / fmaxf(hA + ca[cbase + jj] - inter, 1e-9f);
                if (iou > 0.6f) m |= 1ULL << jj;
            }
            if (w == iw0) m &= (0xFFFFFFFFFFFFFFFEULL << (i & 63));  // keep only j > i
        }
        wbuf[k] = m;
    }
    unsigned long long* Mrow = mask + ((size_t)b * MROWS + (size_t)i) * 80 + cg8;
    if (iw0 <= cg8) {
        ((ulonglong2*)Mrow)[0] = make_ulonglong2(wbuf[0], wbuf[1]);
        ((ulonglong2*)Mrow)[1] = make_ulonglong2(wbuf[2], wbuf[3]);
        ((ulonglong2*)Mrow)[2] = make_ulonglong2(wbuf[4], wbuf[5]);
        ((ulonglong2*)Mrow)[3] = make_ulonglong2(wbuf[6], wbuf[7]);
    } else {
#pragma unroll
        for (int k = 0; k < 8; ++k)
            if (cg8 + k >= iw0) Mrow[k] = wbuf[k];
    }
}

// ---------------- Kernel S: bitmask scan, 64-row groups, ONE barrier per group ----------
// (r17, verified absmax-0; see r17 comments for the slot-liveness proof)
__global__ __launch_bounds__(256, 1) void k_scan(const unsigned int* __restrict__ validWS,
                                                 const unsigned long long* __restrict__ mask,
                                                 const float* __restrict__ scoresWS,
                                                 unsigned long long* __restrict__ keepw,
                                                 float* __restrict__ threshB) {
    __shared__ unsigned long long slots[3 * (SLOTB / 8)];  // 122880 B
    __shared__ unsigned long long dkArr[GRPS];             // write-once diagonal words
    __shared__ unsigned long long kwLDS[80];
    int b = blockIdx.x;
    int tid = threadIdx.x;
    int wv = tid >> 6;
    int lane = tid & 63;
    int wd = wv * 20 + lane;      // owned word if lane<20 (covers 0..79)
    bool own = (lane < 20);
    const char* Mb = (const char*)(mask + (size_t)b * MROWS * 80);

    unsigned long long rw = 0ULL;
    if (own) {
#pragma unroll 8
        for (int jj = 0; jj < 64; ++jj) {
            int j = wd * 64 + jj;
            unsigned int v = (j < MM) ? validWS[b * MM + j] : 0u;
            rw |= (unsigned long long)(v ? 0u : 1u) << jj;
        }
    }
    if (own && wd == 0) dkArr[0] = rw;  // seed group 0
    __syncthreads();

    auto stage = [&](int g, int s) {
        const char* src = Mb + (size_t)g * SLOTB + (size_t)tid * 16;
        unsigned long long* dst = &slots[(size_t)s * (SLOTB / 8)] + (size_t)wv * 128;
#pragma unroll
        for (int j = 0; j < 10; ++j) {
            __builtin_amdgcn_global_load_lds(
                (const __attribute__((address_space(1))) void*)(src + j * 4096),
                (__attribute__((address_space(3))) void*)(dst + j * 512), 16, 0, 0);
        }
    };

    stage(0, 0); stage(1, 1);          // 20 outstanding (prefetch depth 1 group)

    int wdc = own ? wd : 0;
    for (int g = 0; g < GRPS; ++g) {
        asm volatile("s_waitcnt vmcnt(10)" ::: "memory");   // own stage(g) loads landed
        asm volatile("s_waitcnt lgkmcnt(0)" ::: "memory");  // publish(g) ds_write committed
        __builtin_amdgcn_s_barrier();   // all waves: data ready + consume(g-1) done
        __builtin_amdgcn_sched_barrier(0);

        const unsigned long long* sk = &slots[(size_t)(g % 3) * (SLOTB / 8)];
        unsigned long long dcur = dkArr[g];
        unsigned long long gate = (own && wd >= g) ? ~0ULL : 0ULL;
#pragma unroll 4
        for (int c = 0; c < 4; ++c) {
            unsigned long long XD[16], Xs[16];
#pragma unroll
            for (int k = 0; k < 16; ++k) {
                int r = c * 16 + k;
                XD[k] = sk[r * 80 + g];
                Xs[k] = sk[r * 80 + wdc];
            }
            unsigned int alive = 0;
#pragma unroll
            for (int k = 0; k < 16; ++k) {
                int sh_ = c * 16 + k;
                unsigned int a_ = (((dcur >> sh_) & 1ULL) == 0ULL) ? 1u : 0u;
                dcur |= a_ ? XD[k] : 0ULL;
                alive |= a_ << k;
            }
#pragma unroll
            for (int k = 0; k < 16; ++k) {
                unsigned long long m_ = ((alive >> k) & 1u) ? ~0ULL : 0ULL;
                rw |= Xs[k] & m_ & gate;
            }
        }
        if (own && wd == g + 1 && (g + 1) < GRPS) dkArr[g + 1] = rw;
        int gs = (g + 2 < GRPS) ? g + 2 : GRPS - 1;         // uniform load count at tail
        stage(gs, (g + 2) % 3);
    }

    if (own) {
        unsigned long long k0 = ~rw;
        kwLDS[wd] = k0;
        keepw[b * 80 + wd] = k0;
    }
    __syncthreads();
    if (tid == 0) {
        int ndet = 0;
        for (int w = 0; w < 80; ++w) ndet += __popcll(kwLDS[w]);
        float th = -INFINITY;
        if (ndet > 100) {
            int cum = 0, pos = -1;
            for (int w = 0; w < 80 && pos < 0; ++w) {
                int c = __popcll(kwLDS[w]);
                if (cum + c >= 100) {
                    unsigned long long word = kwLDS[w];
                    for (int bb = 0; bb < 64; ++bb) {
                        cum += (int)((word >> bb) & 1ULL);
                        if (cum == 100) { pos = w * 64 + bb; break; }
                    }
                } else {
                    cum += c;
                }
            }
            th = scoresWS[b * MM + pos];
        }
        threshB[b] = th;
    }
}

// ---------------- Kernel Z: masked output write ----------------
__global__ void k_final(const float4* __restrict__ boxesWS, const float* __restrict__ scoresWS,
                        const float* __restrict__ clsWS, const unsigned long long* __restrict__ keepw,
                        const float* __restrict__ threshB, float* __restrict__ out) {
    int g = blockIdx.x * blockDim.x + threadIdx.x;
    if (g >= NB * MM) return;
    int b = g / MM;
    int p = g - b * MM;
    bool kb = (keepw[b * 80 + (p >> 6)] >> (p & 63)) & 1ULL;
    float s = scoresWS[g];
    float th = threshB[b];
    bool k = kb && (s >= th) && (s >= 0.05f);
    float km = k ? 1.0f : 0.0f;
    float4 v = boxesWS[g];
    float* ob = out;
    float* os = out + NB * MM * 4;
    float* oc = out + NB * MM * 5;
    float* ok = out + NB * MM * 6;
    ((float4*)ob)[g] = make_float4(v.x * km, v.y * km, v.z * km, v.w * km);
    os[g] = s * km;
    oc[g] = clsWS[g] * km;
    ok[g] = km;
}

// ---------------- Fallback path (ws too small): original scalar kernels ----------------
__global__ void k_hist_fb(const float* __restrict__ cls, const float* __restrict__ ctr,
                          unsigned int* __restrict__ hist) {
    const long long total = (long long)NB * EPB;
    for (long long e = (long long)blockIdx.x * blockDim.x + threadIdx.x; e < total;
         e += (long long)gridDim.x * blockDim.x) {
        float x = cls[e];
        if (x <= -2.945f) continue;
        double sd = 1.0 / (1.0 + exp(-(double)x));
        float sf = (float)sd;
        if (!(sf > 0.05f)) continue;
        int b = (int)(e / EPB);
        int r = (int)(e - (long long)b * EPB);
        int l = level_of(r);
        int locg = r / 80;
        float c = ctr[(long long)b * NLOC + locg];
        double cd = 1.0 / (1.0 + exp(-(double)c));
        float val = sf * (float)cd;
        unsigned int vb = __float_as_uint(val);
        atomicAdd(&hist[(((long long)b * 5 + l) << 15) + (vb >> 15)], 1u);
    }
}
__global__ void k_cutoff_fb(const unsigned int* __restrict__ hist, unsigned int* __restrict__ bcut) {
    int g = blockIdx.x;
    const unsigned int* h = hist + ((long long)g << 15);
    __shared__ unsigned int ssum[256];
    int t = threadIdx.x;
    unsigned int s = 0;
    for (int i = 0; i < 128; i++) s += h[t * 128 + i];
    ssum[t] = s;
    __syncthreads();
    if (t == 0) {
        unsigned int cum = 0;
        int bucket = 0;
        int ch = 255;
        for (; ch >= 0; ch--) {
            if (cum + ssum[ch] >= 1000u) break;
            cum += ssum[ch];
        }
        if (ch >= 0) {
            int bi = ch * 128 + 127;
            for (; bi > ch * 128; bi--) {
                unsigned int c = h[bi];
                if (cum + c >= 1000u) break;
                cum += c;
            }
            bucket = bi;
        }
        bcut[g] = (unsigned int)bucket;
    }
}
__global__ void k_compact_fb(const float* __restrict__ cls, const float* __restrict__ ctr,
                             const unsigned int* __restrict__ bcut, unsigned int* __restrict__ cnt,
                             unsigned long long* __restrict__ compact) {
    const long long total = (long long)NB * EPB;
    for (long long e = (long long)blockIdx.x * blockDim.x + threadIdx.x; e < total;
         e += (long long)gridDim.x * blockDim.x) {
        float x = cls[e];
        if (x <= -2.945f) continue;
        double sd = 1.0 / (1.0 + exp(-(double)x));
        float sf = (float)sd;
        if (!(sf > 0.05f)) continue;
        int b = (int)(e / EPB);
        int r = (int)(e - (long long)b * EPB);
        int l = level_of(r);
        int locg = r / 80;
        float c = ctr[(long long)b * NLOC + locg];
        double cd = 1.0 / (1.0 + exp(-(double)c));
        float val = sf * (float)cd;
        unsigned int vb = __float_as_uint(val);
        int g = b * 5 + l;
        if ((vb >> 15) >= bcut[g]) {
            unsigned int pos = atomicAdd(&cnt[g], 1u);
            if (pos < CAP) {
                unsigned int idx = (unsigned int)(r - d_estart[l]);
                compact[(long long)g * CAP + pos] =
                    ((unsigned long long)vb << 21) | (unsigned long long)(0x1FFFFFu - idx);
            }
        }
    }
}
__global__ __launch_bounds__(1024) void k_nms(const float4* __restrict__ boxesWS,
                                              const float* __restrict__ scoresWS,
                                              const float* __restrict__ clsWS,
                                              const unsigned int* __restrict__ validWS,
                                              float* __restrict__ out) {
    int b = blockIdx.x;
    int t = threadIdx.x;
    __shared__ unsigned char kf[MM];
    __shared__ int s_min;
    __shared__ int s_cnt;
    float4 bx[5];
    float ar[5];
    int base = b * MM;
    for (int c = 0; c < 5; c++) {
        int p = t + 1024 * c;
        bx[c] = make_float4(0.f, 0.f, 0.f, 0.f);
        ar[c] = 0.f;
        if (p < MM) {
            kf[p] = (unsigned char)validWS[base + p];
            float4 v = boxesWS[base + p];
            bx[c] = v;
            ar[c] = (v.z - v.x) * (v.w - v.y);
        }
    }
    __syncthreads();
    int i = -1;
    while (true) {
        int nh = -1;
        int wstart = i + 1;
        while (wstart < MM) {
            if (t == 0) s_min = 0x7FFFFFFF;
            __syncthreads();
            int p = wstart + t;
            if (p < MM && kf[p]) atomicMin(&s_min, p);
            __syncthreads();
            int sm = s_min;
            __syncthreads();
            if (sm != 0x7FFFFFFF) { nh = sm; break; }
            wstart += 1024;
        }
        if (nh < 0) break;
        i = nh;
        float4 hb = boxesWS[base + i];
        float ha = (hb.z - hb.x) * (hb.w - hb.y);
        for (int c = 0; c < 5; c++) {
            int p = t + 1024 * c;
            if (p > i && p < MM && kf[p]) {
                float xi1 = fmaxf(hb.x, bx[c].x);
                float yi1 = fmaxf(hb.y, bx[c].y);
                float xi2 = fminf(hb.z, bx[c].z);
                float yi2 = fminf(hb.w, bx[c].w);
                float inter = fmaxf(xi2 - xi1, 0.f) * fmaxf(yi2 - yi1, 0.f);
                float iou = inter / fmaxf(ha + ar[c] - inter, 1e-9f);
                if (iou > 0.6f) kf[p] = 0;
            }
        }
        __syncthreads();
    }
    if (t == 0) s_cnt = 0;
    __syncthreads();
    int lc = 0;
    for (int c = 0; c < 5; c++) {
        int p = t + 1024 * c;
        if (p < MM && kf[p]) lc++;
    }
    if (lc) atomicAdd(&s_cnt, lc);
    __syncthreads();
    int n_det = s_cnt;
    float thresh = -INFINITY;
    if (n_det > 100) {
        int lo = 0, hi = MM - 1;
        while (lo < hi) {
            int mid = (lo + hi) >> 1;
            __syncthreads();
            if (t == 0) s_cnt = 0;
            __syncthreads();
            int c2 = 0;
            for (int c = 0; c < 5; c++) {
                int p = t + 1024 * c;
                if (p < MM && p <= mid && kf[p]) c2++;
            }
            if (c2) atomicAdd(&s_cnt, c2);
            __syncthreads();
            if (s_cnt >= 100) hi = mid; else lo = mid + 1;
            __syncthreads();
        }
        thresh = scoresWS[base + lo];
    }
    float* ob = out;
    float* os = out + NB * MM * 4;
    float* oc = out + NB * MM * 5;
    float* ok = out + NB * MM * 6;
    for (int c = 0; c < 5; c++) {
        int p = t + 1024 * c;
        if (p < MM) {
            int g = base + p;
            float s = scoresWS[g];
            bool k = kf[p] && (s >= thresh) && (s >= 0.05f);
            float km = k ? 1.0f : 0.0f;
            float4 v = bx[c];
            ((float4*)ob)[g] = make_float4(v.x * km, v.y * km, v.z * km, v.w * km);
            os[g] = s * km;
            oc[g] = clsWS[g] * km;
            ok[g] = km;
        }
    }
}

extern "C" void kernel_launch(void* const* d_in, const int* in_sizes, int n_in,
                              void* d_out, int out_size, void* d_ws, size_t ws_size,
                              hipStream_t stream) {
    const float* cls = (const float*)d_in[0];
    const float* reg = (const float*)d_in[1];
    const float* ctr = (const float*)d_in[2];
    const float* locs = (const float*)d_in[3];
    (void)in_sizes; (void)n_in; (void)out_size;

    char* ws = (char*)d_ws;
    // fast-path layout (cand aliases mask region -- disjoint lifetimes:
    // cand dies at k_filter, mask born at k_mask)
    unsigned int* cnt = (unsigned int*)(ws);                             // 512
    unsigned int* bcut = (unsigned int*)(ws + 512);                      // 512
    unsigned int* candCnt = (unsigned int*)(ws + 1024);                  // 512
    unsigned int* ovf = (unsigned int*)(ws + 1536);                      // 512
    unsigned long long* compact = (unsigned long long*)(ws + 2048);      // 2,621,440
    unsigned long long* pool = (unsigned long long*)(ws + 2623488);      // 640,000
    unsigned long long* sorted = (unsigned long long*)(ws + 3263488);    // 640,000
    float4* boxesWS = (float4*)(ws + 3903488);                           // 1,280,000
    float* scoresWS = (float*)(ws + 5183488);                            // 320,000
    float* clsWS = (float*)(ws + 5503488);                               // 320,000
    unsigned int* validWS = (unsigned int*)(ws + 5823488);               // 320,000
    unsigned long long* keepw = (unsigned long long*)(ws + 6143488);     // 10,240
    float* threshB = (float*)(ws + 6153728);                             // 256
    float* sigc = (float*)(ws + 6153984);                                // 1,396,736
    unsigned long long* mask = (unsigned long long*)(ws + 7550720);      // 51,773,440
    unsigned long long* cand = (unsigned long long*)(ws + 7550720);      // 55,869,440 (alias)
    const size_t WS_NEED = 7550720ULL + 55869440ULL + 4096ULL;           // 63,424,256

    if (ws_size >= WS_NEED) {
        hipMemsetAsync(ws, 0, 2048, stream);  // cnt + bcut + candCnt + ovf
        hipLaunchKernelGGL(k_ctr, dim3((NB * NLOC + 255) / 256), dim3(256), 0, stream, ctr, sigc);
        hipLaunchKernelGGL(k_fused, dim3(NB * NCHUNK), dim3(1024), 0, stream,
                           cls, sigc, candCnt, cand, ovf);
        hipLaunchKernelGGL(k_cutoff2, dim3(80), dim3(1024), 0, stream,
                           candCnt, cand, ovf, cls, sigc, bcut);
        hipLaunchKernelGGL(k_filter, dim3(80 * 16), dim3(256), 0, stream,
                           candCnt, cand, ovf, bcut, cls, sigc, cnt, compact);
        hipLaunchKernelGGL(k_select, dim3(80), dim3(1024), 0, stream, cnt, compact, pool);
        hipLaunchKernelGGL(k_merge, dim3(NB), dim3(1024), 0, stream, pool, cnt, sorted);
        hipLaunchKernelGGL(k_decode, dim3((NB * MM + 255) / 256), dim3(256), 0, stream,
                           sorted, reg, locs, boxesWS, scoresWS, clsWS, validWS);
        hipLaunchKernelGGL(k_mask, dim3(NB * 110), dim3(256), 0, stream, boxesWS, mask);
        hipLaunchKernelGGL(k_scan, dim3(NB), dim3(256), 0, stream,
                           validWS, mask, scoresWS, keepw, threshB);
        hipLaunchKernelGGL(k_final, dim3((NB * MM + 511) / 512), dim3(512), 0, stream,
                           boxesWS, scoresWS, clsWS, keepw, threshB, (float*)d_out);
    } else {
        // fallback layout (original): hist at 0
        unsigned int* histF = (unsigned int*)(ws);                           // 10,485,760
        unsigned int* cntF = (unsigned int*)(ws + 10485760);                 // 512
        unsigned int* bcutF = (unsigned int*)(ws + 10486272);                // 512
        unsigned long long* compactF = (unsigned long long*)(ws + 10486784); // 2,621,440
        unsigned long long* poolF = (unsigned long long*)(ws + 13108224);    // 640,000
        unsigned long long* sortedF = (unsigned long long*)(ws + 13748224);  // 640,000
        float4* boxesF = (float4*)(ws + 14388224);                           // 1,280,000
        float* scoresF = (float*)(ws + 15668224);                            // 320,000
        float* clsF = (float*)(ws + 15988224);                               // 320,000
        unsigned int* validF = (unsigned int*)(ws + 16308224);               // 320,000
        hipMemsetAsync(ws, 0, 10486784, stream);
        hipLaunchKernelGGL(k_hist_fb, dim3(4096), dim3(256), 0, stream, cls, ctr, histF);
        hipLaunchKernelGGL(k_cutoff_fb, dim3(80), dim3(256), 0, stream, histF, bcutF);
        hipLaunchKernelGGL(k_compact_fb, dim3(4096), dim3(256), 0, stream, cls, ctr, bcutF, cntF, compactF);
        hipLaunchKernelGGL(k_select, dim3(80), dim3(1024), 0, stream, cntF, compactF, poolF);
        hipLaunchKernelGGL(k_merge, dim3(NB), dim3(1024), 0, stream, poolF, cntF, sortedF);
        hipLaunchKernelGGL(k_decode, dim3((NB * MM + 255) / 256), dim3(256), 0, stream,
                           sortedF, reg, locs, boxesF, scoresF, clsF, validF);
        hipLaunchKernelGGL(k_nms, dim3(NB), dim3(1024), 0, stream,
                           boxesF, scoresF, clsF, validF, (float*)d_out);
    }
}

// Round 19
// 774.425 us; speedup vs baseline: 1.0266x; 1.0266x over previous
//
#include <hip/hip_runtime.h>
#include <math.h>

#define NB 16
#define NLOC 21824
#define NCLS 80
#define NLVL 5
#define MM 5000
#define MROWS 5056      // 79 groups x 64 rows (group == diagonal word)
#define GRPS 79
#define SLOTB 40960     // bytes per slot = 64 rows * 640B
#define CAP 4096
#define EPB 1745920     // entries per batch = NLOC*NCLS
#define NCHUNK 16       // fused-pass chunks per batch (level-aligned)
#define NBUCK 16384     // vb>>16 buckets (vb < 2^30)
#define CAND_PB 436480  // candidate keys per batch (25% of each level's entries)
#define WBUF 256        // keys per wave-private staging buffer
#define BSLACK 4        // cutoff slack buckets (fast-key hist error <=1-2; 2x margin)

__device__ __forceinline__ int level_of(int r) {
    return (r < 1310720) ? 0 : (r < 1638400) ? 1 : (r < 1720320) ? 2 : (r < 1740800) ? 3 : 4;
}
__device__ __constant__ int d_estart[5] = {0, 1310720, 1638400, 1720320, 1740800};
__device__ __constant__ int d_lstart[5] = {0, 16384, 20480, 21504, 21760};
// candidate-list layout (keys): per-level capacity = entries/4, per-batch offsets
__device__ __constant__ int d_ccap[5] = {327680, 81920, 20480, 5120, 1280};
__device__ __constant__ int d_coff[5] = {0, 327680, 409600, 430080, 435200};
// k_mask block map: per-batch 110 blocks; start offset per row-chunk rc (cg_min = rc/2)
__device__ __constant__ int d_mstart[20] = {0,10,20,29,38,46,54,61,68,74,80,85,90,94,98,101,104,106,108,109};
// fused-pass chunk tables (entry offsets within batch; each chunk inside one level)
__device__ __constant__ int d_cstart[NCHUNK] = {0,131072,262144,393216,524288,655360,786432,917504,
                                                1048576,1179648,1310720,1441792,1572864,1638400,1720320,1740800};
__device__ __constant__ int d_csize[NCHUNK]  = {131072,131072,131072,131072,131072,131072,131072,131072,
                                                131072,131072,131072,131072,65536,81920,20480,5120};

// ---------------- Kernel P: centerness sigmoid table (bit-identical to reference) --------
__global__ void k_ctr(const float* __restrict__ ctr, float* __restrict__ sigc) {
    int i = blockIdx.x * 256 + threadIdx.x;
    if (i < NB * NLOC) {
        float c = ctr[i];
        sigc[i] = (float)(1.0 / (1.0 + exp(-(double)c)));
    }
}

// ---------------- Kernel A''': ONE cls pass -> FAST candidate keys (r18, verified) ------
__global__ __launch_bounds__(1024) void k_fused(const float* __restrict__ cls,
                                                const float* __restrict__ sigc,
                                                unsigned int* __restrict__ candCnt,
                                                unsigned long long* __restrict__ cand,
                                                unsigned int* __restrict__ ovf) {
    __shared__ unsigned long long wbuf[16 * WBUF];   // 32768 B
    int blk = blockIdx.x;
    int b = blk >> 4;
    int c = blk & 15;
    int tid = threadIdx.x;
    int lane = tid & 63;
    int wslot = (tid >> 6) * WBUF;
    int n4 = d_csize[c] >> 2;
    int r0base = d_cstart[c];
    int l = level_of(r0base);          // chunk is level-uniform
    int g = b * 5 + l;
    unsigned int capg = (unsigned int)d_ccap[l];
    unsigned long long* cg = cand + (size_t)b * CAND_PB + d_coff[l];
    const float4* src = (const float4*)(cls + ((long long)b * EPB + r0base));

    unsigned int wbase = 0;   // wave-uniform count of keys staged in this wave's buffer

    auto flushw = [&]() {     // wave-converged only
        if (wbase > 0) {
            unsigned int gbase = 0;
            if (lane == 0) gbase = atomicAdd(&candCnt[g], wbase);
            gbase = (unsigned int)__shfl((int)gbase, 0, 64);
            for (unsigned int k = (unsigned int)lane; k < wbase; k += 64) {
                unsigned int my = gbase + k;
                if (my < capg) cg[my] = wbuf[wslot + k];
                else ovf[g] = 1u;
            }
            wbase = 0;
        }
    };

    for (int i = tid; i < n4; i += 1024) {
        float4 x4 = src[i];
        int r0 = r0base + i * 4;
        bool any = !(x4.x <= -2.945f && x4.y <= -2.945f && x4.z <= -2.945f && x4.w <= -2.945f);
        float cf = 0.f;
        if (any) cf = sigc[b * NLOC + r0 / 80];   // 4 | 80: all 4 share the location
        float xs[4] = {x4.x, x4.y, x4.z, x4.w};
#pragma unroll
        for (int j = 0; j < 4; ++j) {
            float x = xs[j];
            bool pass = false;
            unsigned long long key = 0ULL;
            if (x > -2.945f) {                         // exact sf there <=0.049968 -> fast fails too
                float sf = 1.0f / (1.0f + __expf(-x)); // FAST (key refined in k_filter)
                if (sf > 0.049999f) {                  // widened gate: superset of exact
                    float val = sf * cf;
                    unsigned int vb = __float_as_uint(val);
                    unsigned int idx = (unsigned int)(r0 + j - d_estart[l]);
                    key = ((unsigned long long)vb << 21) | (unsigned long long)(0x1FFFFFu - idx);
                    pass = true;
                }
            }
            unsigned long long mk = __ballot(pass);
            unsigned int wcnt = (unsigned int)__popcll(mk);
            if (wbase + wcnt > WBUF) flushw();
            if (pass) {
                unsigned int pos = wbase + (unsigned int)__popcll(mk & ((1ULL << lane) - 1ULL));
                wbuf[wslot + pos] = key;
            }
            wbase += wcnt;
        }
    }
    flushw();
}

// ---------------- Kernel B'': cutoff bucket from fast keys, slack applied --------
__global__ __launch_bounds__(1024) void k_cutoff2(const unsigned int* __restrict__ candCnt,
                                                  const unsigned long long* __restrict__ cand,
                                                  const unsigned int* __restrict__ ovf,
                                                  const float* __restrict__ cls,
                                                  const float* __restrict__ sigc,
                                                  unsigned int* __restrict__ bcut) {
    __shared__ unsigned int lh[NBUCK];   // 65536 B
    __shared__ unsigned int ssum[1024];
    int g = blockIdx.x;  // 0..79
    int b = g / 5, l = g % 5;
    int tid = threadIdx.x;
    for (int i = tid; i < NBUCK; i += 1024) lh[i] = 0;
    __syncthreads();
    bool fastpath = !ovf[g];
    if (fastpath) {
        int n = min((int)candCnt[g], d_ccap[l]);
        const unsigned long long* cg = cand + (size_t)b * CAND_PB + d_coff[l];
        for (int i = tid; i < n; i += 1024) {
            unsigned int vb = (unsigned int)(cg[i] >> 21);
            atomicAdd(&lh[vb >> 16], 1u);
        }
    } else {
        // exact fallback: rescan this level's cls region (never expected)
        int start = d_estart[l];
        int sz4 = (((l < 4) ? d_estart[l + 1] : EPB) - start) >> 2;
        const float4* src = (const float4*)(cls + ((long long)b * EPB + start));
        for (int i = tid; i < sz4; i += 1024) {
            float4 x4 = src[i];
            if (x4.x <= -2.945f && x4.y <= -2.945f && x4.z <= -2.945f && x4.w <= -2.945f)
                continue;
            int r0 = start + i * 4;
            float cf = sigc[b * NLOC + r0 / 80];
            float xs[4] = {x4.x, x4.y, x4.z, x4.w};
#pragma unroll
            for (int j = 0; j < 4; ++j) {
                float x = xs[j];
                if (x <= -2.945f) continue;
                double sd = 1.0 / (1.0 + exp(-(double)x));
                float sf = (float)sd;
                if (!(sf > 0.05f)) continue;
                unsigned int vb = __float_as_uint(sf * cf);
                atomicAdd(&lh[vb >> 16], 1u);
            }
        }
    }
    __syncthreads();
    unsigned int s2 = 0;
    for (int k = 0; k < 16; ++k) s2 += lh[tid * 16 + k];
    ssum[tid] = s2;
    __syncthreads();
    if (tid == 0) {
        unsigned int cum = 0;
        int bucket = 0;
        int ch = 1023;
        for (; ch >= 0; ch--) {
            if (cum + ssum[ch] >= 1000u) break;
            cum += ssum[ch];
        }
        if (ch >= 0) {
            int bi = ch * 16 + 15;
            for (; bi > ch * 16; bi--) {
                unsigned int cc = lh[bi];
                if (cum + cc >= 1000u) break;
                cum += cc;
            }
            bucket = bi;
        }
        if (fastpath) bucket = (bucket > BSLACK) ? bucket - BSLACK : 0;  // slack: fast keys
        bcut[g] = (unsigned int)bucket;
    }
}

// ---------------- Kernel C'': filter fast keys; EXACT key recompute for survivors -------
__global__ __launch_bounds__(256) void k_filter(const unsigned int* __restrict__ candCnt,
                                                const unsigned long long* __restrict__ cand,
                                                const unsigned int* __restrict__ ovf,
                                                const unsigned int* __restrict__ bcut,
                                                const float* __restrict__ cls,
                                                const float* __restrict__ sigc,
                                                unsigned int* __restrict__ cnt,
                                                unsigned long long* __restrict__ compact) {
    int id = blockIdx.x;          // 80 g x 16 sub
    int g = id >> 4;
    int sub = id & 15;
    int b = g / 5, l = g % 5;
    int tid = threadIdx.x;
    unsigned int bc = bcut[g];
    if (!ovf[g]) {
        int n = min((int)candCnt[g], d_ccap[l]);
        const unsigned long long* cg = cand + (size_t)b * CAND_PB + d_coff[l];
        int start = d_estart[l];
        for (int i = sub * 256 + tid; i < n; i += 4096) {
            unsigned long long key = cg[i];
            unsigned int vb = (unsigned int)(key >> 21);
            if ((vb >> 16) >= bc) {
                // survivor: recompute EXACT key (bit-identical to reference math)
                unsigned int idx = 0x1FFFFFu - (unsigned int)(key & 0x1FFFFFu);
                int e = start + (int)idx;
                float x = cls[(long long)b * EPB + e];
                float cf = sigc[b * NLOC + e / 80];
                double sd = 1.0 / (1.0 + exp(-(double)x));
                float sf = (float)sd;
                if (sf > 0.05f) {
                    unsigned int vbe = __float_as_uint(sf * cf);
                    unsigned int pos = atomicAdd(&cnt[g], 1u);
                    if (pos < CAP)
                        compact[(long long)g * CAP + pos] =
                            ((unsigned long long)vbe << 21) | (unsigned long long)(0x1FFFFFu - idx);
                }
            }
        }
    } else {
        // exact fallback: rescan level (never expected)
        int start = d_estart[l];
        int sz4 = (((l < 4) ? d_estart[l + 1] : EPB) - start) >> 2;
        const float4* src = (const float4*)(cls + ((long long)b * EPB + start));
        for (int i = sub * 256 + tid; i < sz4; i += 4096) {
            float4 x4 = src[i];
            if (x4.x <= -2.945f && x4.y <= -2.945f && x4.z <= -2.945f && x4.w <= -2.945f)
                continue;
            int r0 = start + i * 4;
            float cf = sigc[b * NLOC + r0 / 80];
            float xs[4] = {x4.x, x4.y, x4.z, x4.w};
#pragma unroll
            for (int j = 0; j < 4; ++j) {
                float x = xs[j];
                if (x <= -2.945f) continue;
                double sd = 1.0 / (1.0 + exp(-(double)x));
                float sf = (float)sd;
                if (!(sf > 0.05f)) continue;
                unsigned int vb = __float_as_uint(sf * cf);
                if ((vb >> 16) >= bc) {
                    unsigned int idx = (unsigned int)(r0 + j - d_estart[l]);
                    unsigned int pos = atomicAdd(&cnt[g], 1u);
                    if (pos < CAP)
                        compact[(long long)g * CAP + pos] =
                            ((unsigned long long)vb << 21) | (unsigned long long)(0x1FFFFFu - idx);
                }
            }
        }
    }
}

// ---------------- Kernel D: per-(b,l) bitonic sort + build global keys ----------------
__global__ void k_select(const unsigned int* __restrict__ cnt,
                         const unsigned long long* __restrict__ compact,
                         unsigned long long* __restrict__ pool) {
    __shared__ unsigned long long sk[CAP];
    int g = blockIdx.x;
    int b = g / 5, l = g % 5;
    int count = min((int)cnt[g], CAP);
    for (int p = threadIdx.x; p < CAP; p += blockDim.x)
        sk[p] = (p < count) ? compact[(long long)g * CAP + p] : 0ULL;
    __syncthreads();
    for (int k = 2; k <= CAP; k <<= 1) {
        for (int j = k >> 1; j > 0; j >>= 1) {
            for (int i = threadIdx.x; i < CAP; i += blockDim.x) {
                int ixj = i ^ j;
                if (ixj > i) {
                    unsigned long long a = sk[i], bb = sk[ixj];
                    bool desc = ((i & k) == 0);
                    if (desc ? (a < bb) : (a > bb)) { sk[i] = bb; sk[ixj] = a; }
                }
            }
            __syncthreads();
        }
    }
    int ksel = min(1000, count);
    for (int r = threadIdx.x; r < 1000; r += blockDim.x) {
        unsigned long long gk = 0ULL;
        if (r < ksel) {
            unsigned long long key = sk[r];
            unsigned int vb = (unsigned int)(key >> 21);
            unsigned int idx = 0x1FFFFFu - (unsigned int)(key & 0x1FFFFFu);
            float val = __uint_as_float(vb);
            float sc = sqrtf(val);
            unsigned long long sb = (unsigned long long)__float_as_uint(sc);
            gk = (sb << 34) | ((unsigned long long)(7 - l) << 31) |
                 ((unsigned long long)(1023 - r) << 21) | (unsigned long long)idx;
        }
        pool[(long long)b * MM + l * 1000 + r] = gk;
    }
}

// ---------------- Kernel E': 5-way merge by exact rank ----------------
__global__ __launch_bounds__(1024) void k_merge(const unsigned long long* __restrict__ pool,
                                                const unsigned int* __restrict__ cnt,
                                                unsigned long long* __restrict__ sorted) {
    __shared__ unsigned long long sp[MM];
    __shared__ int s_nz[5];
    int b = blockIdx.x, t = threadIdx.x;
    for (int p = t; p < MM; p += 1024) sp[p] = pool[(long long)b * MM + p];
    if (t < 5) s_nz[t] = (int)min(cnt[b * 5 + t], 1000u);
    __syncthreads();
    int nzTot = s_nz[0] + s_nz[1] + s_nz[2] + s_nz[3] + s_nz[4];
    for (int p = t; p < MM; p += 1024) {
        int l = p / 1000, r = p - l * 1000;
        unsigned long long K = sp[p];
        int rank;
        if (K) {
            rank = r;
#pragma unroll
            for (int l2 = 0; l2 < 5; ++l2) {
                if (l2 == l) continue;
                const unsigned long long* L = sp + l2 * 1000;
                int lo = 0, hi = s_nz[l2];
                while (lo < hi) {
                    int mid = (lo + hi) >> 1;
                    if (L[mid] > K) lo = mid + 1; else hi = mid;
                }
                rank += lo;
            }
        } else {
            int zi = 0;
#pragma unroll
            for (int l2 = 0; l2 < 5; ++l2) if (l2 < l) zi += 1000 - s_nz[l2];
            zi += r - s_nz[l];
            rank = nzTot + zi;
        }
        sorted[(long long)b * MM + rank] = K;
    }
}

// ---------------- Kernel F: decode boxes/scores/classes ----------------
__global__ void k_decode(const unsigned long long* __restrict__ sorted,
                         const float* __restrict__ reg, const float* __restrict__ locs,
                         float4* __restrict__ boxesWS, float* __restrict__ scoresWS,
                         float* __restrict__ clsWS, unsigned int* __restrict__ validWS) {
    int g = blockIdx.x * blockDim.x + threadIdx.x;
    if (g >= NB * MM) return;
    int b = g / MM;
    unsigned long long gk = sorted[g];
    float4 bx = make_float4(0.f, 0.f, 0.f, 0.f);
    float sc = 0.f, cf = 0.f;
    unsigned int v = 0;
    if (gk) {
        sc = __uint_as_float((unsigned int)(gk >> 34));
        int l = 7 - (int)((gk >> 31) & 7);
        int idx = (int)(gk & 0x1FFFFF);
        int loc = idx / 80;
        int c = idx - loc * 80;
        int gl = d_lstart[l] + loc;
        float lx = locs[gl * 2], ly = locs[gl * 2 + 1];
        const float* r4 = reg + ((long long)b * NLOC + gl) * 4;
        float x1 = fminf(fmaxf(lx - r4[0], 0.f), 1024.f);
        float y1 = fminf(fmaxf(ly - r4[1], 0.f), 1024.f);
        float x2 = fminf(fmaxf(lx + r4[2], 0.f), 1024.f);
        float y2 = fminf(fmaxf(ly + r4[3], 0.f), 1024.f);
        bx = make_float4(x1, y1, x2, y2);
        cf = (float)(c + 1);
        v = 1;
    }
    boxesWS[g] = bx;
    scoresWS[g] = sc;
    clsWS[g] = cf;
    validWS[g] = v;
}

// ---------------- Kernel M: pairwise suppression bitmask (tiled) ----------------
__global__ __launch_bounds__(256) void k_mask(const float4* __restrict__ boxesWS,
                                              unsigned long long* __restrict__ mask) {
    __shared__ float4 cb[512];
    __shared__ float ca[512];
    int id = blockIdx.x;
    int b = id / 110;
    int q = id - b * 110;
    int rc = 19;
    for (int r = 1; r < 20; ++r) if (q < d_mstart[r]) { rc = r - 1; break; }
    int cg = rc / 2 + (q - d_mstart[rc]);
    int t = threadIdx.x;
    int i = rc * 256 + t;
    int c0 = cg * 512;
    for (int c = t; c < 512; c += 256) {
        int j = c0 + c;
        float4 v = (j < MM) ? boxesWS[b * MM + j] : make_float4(0.f, 0.f, 0.f, 0.f);
        cb[c] = v;
        ca[c] = (v.z - v.x) * (v.w - v.y);
    }
    __syncthreads();
    if (i >= MM) return;
    float4 hb = boxesWS[b * MM + i];
    float hA = (hb.z - hb.x) * (hb.w - hb.y);
    int iw0 = i >> 6;
    int cg8 = cg * 8;
    unsigned long long wbuf[8];
#pragma unroll
    for (int k = 0; k < 8; ++k) {
        int w = cg8 + k;
        unsigned long long m = 0ULL;
        if (w >= iw0) {
            int cbase = w * 64 - c0;
            for (int jj = 0; jj < 64; ++jj) {
                float4 cbj = cb[cbase + jj];
                float xi1 = fmaxf(hb.x, cbj.x);
                float yi1 = fmaxf(hb.y, cbj.y);
                float xi2 = fminf(hb.z, cbj.z);
                float yi2 = fminf(hb.w, cbj.w);
                float inter = fmaxf(xi2 - xi1, 0.f) * fmaxf(yi2 - yi1, 0.f);
                float iou = inter / fmaxf(hA + ca[cbase + jj] - inter, 1e-9f);
                if (iou > 0.6f) m |= 1ULL << jj;
            }
            if (w == iw0) m &= (0xFFFFFFFFFFFFFFFEULL << (i & 63));  // keep only j > i
        }
        wbuf[k] = m;
    }
    unsigned long long* Mrow = mask + ((size_t)b * MROWS + (size_t)i) * 80 + cg8;
    if (iw0 <= cg8) {
        ((ulonglong2*)Mrow)[0] = make_ulonglong2(wbuf[0], wbuf[1]);
        ((ulonglong2*)Mrow)[1] = make_ulonglong2(wbuf[2], wbuf[3]);
        ((ulonglong2*)Mrow)[2] = make_ulonglong2(wbuf[4], wbuf[5]);
        ((ulonglong2*)Mrow)[3] = make_ulonglong2(wbuf[6], wbuf[7]);
    } else {
#pragma unroll
        for (int k = 0; k < 8; ++k)
            if (cg8 + k >= iw0) Mrow[k] = wbuf[k];
    }
}

// ---------------- Kernel S: bitmask scan, alive-gated Xs gather ----------
// Sync skeleton byte-identical to r17/r18 (verified): one barrier/group, 3-slot ring,
// vmcnt(10). NEW (consume only): chain runs first on XD (64 uniform reads/group),
// producing the group's wave-uniform 64-bit alive mask; Xs rows are then gathered
// ONLY for alive rows (~4/group vs 64) -- rows with m_=0 contributed nothing to rw,
// so the algebra is provably identical. LDS instrs/wave/group: 128 -> ~68.
__global__ __launch_bounds__(256, 1) void k_scan(const unsigned int* __restrict__ validWS,
                                                 const unsigned long long* __restrict__ mask,
                                                 const float* __restrict__ scoresWS,
                                                 unsigned long long* __restrict__ keepw,
                                                 float* __restrict__ threshB) {
    __shared__ unsigned long long slots[3 * (SLOTB / 8)];  // 122880 B
    __shared__ unsigned long long dkArr[GRPS];             // write-once diagonal words
    __shared__ unsigned long long kwLDS[80];
    int b = blockIdx.x;
    int tid = threadIdx.x;
    int wv = tid >> 6;
    int lane = tid & 63;
    int wd = wv * 20 + lane;      // owned word if lane<20 (covers 0..79)
    bool own = (lane < 20);
    const char* Mb = (const char*)(mask + (size_t)b * MROWS * 80);

    unsigned long long rw = 0ULL;
    if (own) {
#pragma unroll 8
        for (int jj = 0; jj < 64; ++jj) {
            int j = wd * 64 + jj;
            unsigned int v = (j < MM) ? validWS[b * MM + j] : 0u;
            rw |= (unsigned long long)(v ? 0u : 1u) << jj;
        }
    }
    if (own && wd == 0) dkArr[0] = rw;  // seed group 0
    __syncthreads();

    auto stage = [&](int g, int s) {
        const char* src = Mb + (size_t)g * SLOTB + (size_t)tid * 16;
        unsigned long long* dst = &slots[(size_t)s * (SLOTB / 8)] + (size_t)wv * 128;
#pragma unroll
        for (int j = 0; j < 10; ++j) {
            __builtin_amdgcn_global_load_lds(
                (const __attribute__((address_space(1))) void*)(src + j * 4096),
                (__attribute__((address_space(3))) void*)(dst + j * 512), 16, 0, 0);
        }
    };

    stage(0, 0); stage(1, 1);          // 20 outstanding (prefetch depth 1 group)

    int wdc = own ? wd : 0;
    for (int g = 0; g < GRPS; ++g) {
        asm volatile("s_waitcnt vmcnt(10)" ::: "memory");   // own stage(g) loads landed
        asm volatile("s_waitcnt lgkmcnt(0)" ::: "memory");  // publish(g) ds_write committed
        __builtin_amdgcn_s_barrier();   // all waves: data ready + consume(g-1) done
        __builtin_amdgcn_sched_barrier(0);

        const unsigned long long* sk = &slots[(size_t)(g % 3) * (SLOTB / 8)];
        unsigned long long dcur = dkArr[g];
        unsigned long long gate = (own && wd >= g) ? ~0ULL : 0ULL;
        unsigned long long am = 0ULL;   // group alive mask (wave-uniform)
#pragma unroll 4
        for (int c = 0; c < 4; ++c) {
            unsigned long long XD[16];
#pragma unroll
            for (int k = 0; k < 16; ++k) XD[k] = sk[(c * 16 + k) * 80 + g];
            unsigned int alive = 0;
#pragma unroll
            for (int k = 0; k < 16; ++k) {
                int sh_ = c * 16 + k;
                unsigned int a_ = (((dcur >> sh_) & 1ULL) == 0ULL) ? 1u : 0u;
                dcur |= a_ ? XD[k] : 0ULL;
                alive |= a_ << k;
            }
            am |= (unsigned long long)alive << (c * 16);
        }
        // gather Xs ONLY for alive rows (~4/group); am is uniform -> no divergence
        unsigned long long t = am;
        while (t) {
            int k = __ffsll((long long)t) - 1;
            unsigned long long xv = sk[k * 80 + wdc];
            rw |= xv & gate;
            t &= t - 1;
        }
        if (own && wd == g + 1 && (g + 1) < GRPS) dkArr[g + 1] = rw;
        int gs = (g + 2 < GRPS) ? g + 2 : GRPS - 1;         // uniform load count at tail
        stage(gs, (g + 2) % 3);
    }

    if (own) {
        unsigned long long k0 = ~rw;
        kwLDS[wd] = k0;
        keepw[b * 80 + wd] = k0;
    }
    __syncthreads();
    if (tid == 0) {
        int ndet = 0;
        for (int w = 0; w < 80; ++w) ndet += __popcll(kwLDS[w]);
        float th = -INFINITY;
        if (ndet > 100) {
            int cum = 0, pos = -1;
            for (int w = 0; w < 80 && pos < 0; ++w) {
                int c = __popcll(kwLDS[w]);
                if (cum + c >= 100) {
                    unsigned long long word = kwLDS[w];
                    for (int bb = 0; bb < 64; ++bb) {
                        cum += (int)((word >> bb) & 1ULL);
                        if (cum == 100) { pos = w * 64 + bb; break; }
                    }
                } else {
                    cum += c;
                }
            }
            th = scoresWS[b * MM + pos];
        }
        threshB[b] = th;
    }
}

// ---------------- Kernel Z: masked output write ----------------
__global__ void k_final(const float4* __restrict__ boxesWS, const float* __restrict__ scoresWS,
                        const float* __restrict__ clsWS, const unsigned long long* __restrict__ keepw,
                        const float* __restrict__ threshB, float* __restrict__ out) {
    int g = blockIdx.x * blockDim.x + threadIdx.x;
    if (g >= NB * MM) return;
    int b = g / MM;
    int p = g - b * MM;
    bool kb = (keepw[b * 80 + (p >> 6)] >> (p & 63)) & 1ULL;
    float s = scoresWS[g];
    float th = threshB[b];
    bool k = kb && (s >= th) && (s >= 0.05f);
    float km = k ? 1.0f : 0.0f;
    float4 v = boxesWS[g];
    float* ob = out;
    float* os = out + NB * MM * 4;
    float* oc = out + NB * MM * 5;
    float* ok = out + NB * MM * 6;
    ((float4*)ob)[g] = make_float4(v.x * km, v.y * km, v.z * km, v.w * km);
    os[g] = s * km;
    oc[g] = clsWS[g] * km;
    ok[g] = km;
}

// ---------------- Fallback path (ws too small): original scalar kernels ----------------
__global__ void k_hist_fb(const float* __restrict__ cls, const float* __restrict__ ctr,
                          unsigned int* __restrict__ hist) {
    const long long total = (long long)NB * EPB;
    for (long long e = (long long)blockIdx.x * blockDim.x + threadIdx.x; e < total;
         e += (long long)gridDim.x * blockDim.x) {
        float x = cls[e];
        if (x <= -2.945f) continue;
        double sd = 1.0 / (1.0 + exp(-(double)x));
        float sf = (float)sd;
        if (!(sf > 0.05f)) continue;
        int b = (int)(e / EPB);
        int r = (int)(e - (long long)b * EPB);
        int l = level_of(r);
        int locg = r / 80;
        float c = ctr[(long long)b * NLOC + locg];
        double cd = 1.0 / (1.0 + exp(-(double)c));
        float val = sf * (float)cd;
        unsigned int vb = __float_as_uint(val);
        atomicAdd(&hist[(((long long)b * 5 + l) << 15) + (vb >> 15)], 1u);
    }
}
__global__ void k_cutoff_fb(const unsigned int* __restrict__ hist, unsigned int* __restrict__ bcut) {
    int g = blockIdx.x;
    const unsigned int* h = hist + ((long long)g << 15);
    __shared__ unsigned int ssum[256];
    int t = threadIdx.x;
    unsigned int s = 0;
    for (int i = 0; i < 128; i++) s += h[t * 128 + i];
    ssum[t] = s;
    __syncthreads();
    if (t == 0) {
        unsigned int cum = 0;
        int bucket = 0;
        int ch = 255;
        for (; ch >= 0; ch--) {
            if (cum + ssum[ch] >= 1000u) break;
            cum += ssum[ch];
        }
        if (ch >= 0) {
            int bi = ch * 128 + 127;
            for (; bi > ch * 128; bi--) {
                unsigned int c = h[bi];
                if (cum + c >= 1000u) break;
                cum += c;
            }
            bucket = bi;
        }
        bcut[g] = (unsigned int)bucket;
    }
}
__global__ void k_compact_fb(const float* __restrict__ cls, const float* __restrict__ ctr,
                             const unsigned int* __restrict__ bcut, unsigned int* __restrict__ cnt,
                             unsigned long long* __restrict__ compact) {
    const long long total = (long long)NB * EPB;
    for (long long e = (long long)blockIdx.x * blockDim.x + threadIdx.x; e < total;
         e += (long long)gridDim.x * blockDim.x) {
        float x = cls[e];
        if (x <= -2.945f) continue;
        double sd = 1.0 / (1.0 + exp(-(double)x));
        float sf = (float)sd;
        if (!(sf > 0.05f)) continue;
        int b = (int)(e / EPB);
        int r = (int)(e - (long long)b * EPB);
        int l = level_of(r);
        int locg = r / 80;
        float c = ctr[(long long)b * NLOC + locg];
        double cd = 1.0 / (1.0 + exp(-(double)c));
        float val = sf * (float)cd;
        unsigned int vb = __float_as_uint(val);
        int g = b * 5 + l;
        if ((vb >> 15) >= bcut[g]) {
            unsigned int pos = atomicAdd(&cnt[g], 1u);
            if (pos < CAP) {
                unsigned int idx = (unsigned int)(r - d_estart[l]);
                compact[(long long)g * CAP + pos] =
                    ((unsigned long long)vb << 21) | (unsigned long long)(0x1FFFFFu - idx);
            }
        }
    }
}
__global__ __launch_bounds__(1024) void k_nms(const float4* __restrict__ boxesWS,
                                              const float* __restrict__ scoresWS,
                                              const float* __restrict__ clsWS,
                                              const unsigned int* __restrict__ validWS,
                                              float* __restrict__ out) {
    int b = blockIdx.x;
    int t = threadIdx.x;
    __shared__ unsigned char kf[MM];
    __shared__ int s_min;
    __shared__ int s_cnt;
    float4 bx[5];
    float ar[5];
    int base = b * MM;
    for (int c = 0; c < 5; c++) {
        int p = t + 1024 * c;
        bx[c] = make_float4(0.f, 0.f, 0.f, 0.f);
        ar[c] = 0.f;
        if (p < MM) {
            kf[p] = (unsigned char)validWS[base + p];
            float4 v = boxesWS[base + p];
            bx[c] = v;
            ar[c] = (v.z - v.x) * (v.w - v.y);
        }
    }
    __syncthreads();
    int i = -1;
    while (true) {
        int nh = -1;
        int wstart = i + 1;
        while (wstart < MM) {
            if (t == 0) s_min = 0x7FFFFFFF;
            __syncthreads();
            int p = wstart + t;
            if (p < MM && kf[p]) atomicMin(&s_min, p);
            __syncthreads();
            int sm = s_min;
            __syncthreads();
            if (sm != 0x7FFFFFFF) { nh = sm; break; }
            wstart += 1024;
        }
        if (nh < 0) break;
        i = nh;
        float4 hb = boxesWS[base + i];
        float ha = (hb.z - hb.x) * (hb.w - hb.y);
        for (int c = 0; c < 5; c++) {
            int p = t + 1024 * c;
            if (p > i && p < MM && kf[p]) {
                float xi1 = fmaxf(hb.x, bx[c].x);
                float yi1 = fmaxf(hb.y, bx[c].y);
                float xi2 = fminf(hb.z, bx[c].z);
                float yi2 = fminf(hb.w, bx[c].w);
                float inter = fmaxf(xi2 - xi1, 0.f) * fmaxf(yi2 - yi1, 0.f);
                float iou = inter / fmaxf(ha + ar[c] - inter, 1e-9f);
                if (iou > 0.6f) kf[p] = 0;
            }
        }
        __syncthreads();
    }
    if (t == 0) s_cnt = 0;
    __syncthreads();
    int lc = 0;
    for (int c = 0; c < 5; c++) {
        int p = t + 1024 * c;
        if (p < MM && kf[p]) lc++;
    }
    if (lc) atomicAdd(&s_cnt, lc);
    __syncthreads();
    int n_det = s_cnt;
    float thresh = -INFINITY;
    if (n_det > 100) {
        int lo = 0, hi = MM - 1;
        while (lo < hi) {
            int mid = (lo + hi) >> 1;
            __syncthreads();
            if (t == 0) s_cnt = 0;
            __syncthreads();
            int c2 = 0;
            for (int c = 0; c < 5; c++) {
                int p = t + 1024 * c;
                if (p < MM && p <= mid && kf[p]) c2++;
            }
            if (c2) atomicAdd(&s_cnt, c2);
            __syncthreads();
            if (s_cnt >= 100) hi = mid; else lo = mid + 1;
            __syncthreads();
        }
        thresh = scoresWS[base + lo];
    }
    float* ob = out;
    float* os = out + NB * MM * 4;
    float* oc = out + NB * MM * 5;
    float* ok = out + NB * MM * 6;
    for (int c = 0; c < 5; c++) {
        int p = t + 1024 * c;
        if (p < MM) {
            int g = base + p;
            float s = scoresWS[g];
            bool k = kf[p] && (s >= thresh) && (s >= 0.05f);
            float km = k ? 1.0f : 0.0f;
            float4 v = bx[c];
            ((float4*)ob)[g] = make_float4(v.x * km, v.y * km, v.z * km, v.w * km);
            os[g] = s * km;
            oc[g] = clsWS[g] * km;
            ok[g] = km;
        }
    }
}

extern "C" void kernel_launch(void* const* d_in, const int* in_sizes, int n_in,
                              void* d_out, int out_size, void* d_ws, size_t ws_size,
                              hipStream_t stream) {
    const float* cls = (const float*)d_in[0];
    const float* reg = (const float*)d_in[1];
    const float* ctr = (const float*)d_in[2];
    const float* locs = (const float*)d_in[3];
    (void)in_sizes; (void)n_in; (void)out_size;

    char* ws = (char*)d_ws;
    // fast-path layout (cand aliases mask region -- disjoint lifetimes:
    // cand dies at k_filter, mask born at k_mask)
    unsigned int* cnt = (unsigned int*)(ws);                             // 512
    unsigned int* bcut = (unsigned int*)(ws + 512);                      // 512
    unsigned int* candCnt = (unsigned int*)(ws + 1024);                  // 512
    unsigned int* ovf = (unsigned int*)(ws + 1536);                      // 512
    unsigned long long* compact = (unsigned long long*)(ws + 2048);      // 2,621,440
    unsigned long long* pool = (unsigned long long*)(ws + 2623488);      // 640,000
    unsigned long long* sorted = (unsigned long long*)(ws + 3263488);    // 640,000
    float4* boxesWS = (float4*)(ws + 3903488);                           // 1,280,000
    float* scoresWS = (float*)(ws + 5183488);                            // 320,000
    float* clsWS = (float*)(ws + 5503488);                               // 320,000
    unsigned int* validWS = (unsigned int*)(ws + 5823488);               // 320,000
    unsigned long long* keepw = (unsigned long long*)(ws + 6143488);     // 10,240
    float* threshB = (float*)(ws + 6153728);                             // 256
    float* sigc = (float*)(ws + 6153984);                                // 1,396,736
    unsigned long long* mask = (unsigned long long*)(ws + 7550720);      // 51,773,440
    unsigned long long* cand = (unsigned long long*)(ws + 7550720);      // 55,869,440 (alias)
    const size_t WS_NEED = 7550720ULL + 55869440ULL + 4096ULL;           // 63,424,256

    if (ws_size >= WS_NEED) {
        hipMemsetAsync(ws, 0, 2048, stream);  // cnt + bcut + candCnt + ovf
        hipLaunchKernelGGL(k_ctr, dim3((NB * NLOC + 255) / 256), dim3(256), 0, stream, ctr, sigc);
        hipLaunchKernelGGL(k_fused, dim3(NB * NCHUNK), dim3(1024), 0, stream,
                           cls, sigc, candCnt, cand, ovf);
        hipLaunchKernelGGL(k_cutoff2, dim3(80), dim3(1024), 0, stream,
                           candCnt, cand, ovf, cls, sigc, bcut);
        hipLaunchKernelGGL(k_filter, dim3(80 * 16), dim3(256), 0, stream,
                           candCnt, cand, ovf, bcut, cls, sigc, cnt, compact);
        hipLaunchKernelGGL(k_select, dim3(80), dim3(1024), 0, stream, cnt, compact, pool);
        hipLaunchKernelGGL(k_merge, dim3(NB), dim3(1024), 0, stream, pool, cnt, sorted);
        hipLaunchKernelGGL(k_decode, dim3((NB * MM + 255) / 256), dim3(256), 0, stream,
                           sorted, reg, locs, boxesWS, scoresWS, clsWS, validWS);
        hipLaunchKernelGGL(k_mask, dim3(NB * 110), dim3(256), 0, stream, boxesWS, mask);
        hipLaunchKernelGGL(k_scan, dim3(NB), dim3(256), 0, stream,
                           validWS, mask, scoresWS, keepw, threshB);
        hipLaunchKernelGGL(k_final, dim3((NB * MM + 511) / 512), dim3(512), 0, stream,
                           boxesWS, scoresWS, clsWS, keepw, threshB, (float*)d_out);
    } else {
        // fallback layout (original): hist at 0
        unsigned int* histF = (unsigned int*)(ws);                           // 10,485,760
        unsigned int* cntF = (unsigned int*)(ws + 10485760);                 // 512
        unsigned int* bcutF = (unsigned int*)(ws + 10486272);                // 512
        unsigned long long* compactF = (unsigned long long*)(ws + 10486784); // 2,621,440
        unsigned long long* poolF = (unsigned long long*)(ws + 13108224);    // 640,000
        unsigned long long* sortedF = (unsigned long long*)(ws + 13748224);  // 640,000
        float4* boxesF = (float4*)(ws + 14388224);                           // 1,280,000
        float* scoresF = (float*)(ws + 15668224);                            // 320,000
        float* clsF = (float*)(ws + 15988224);                               // 320,000
        unsigned int* validF = (unsigned int*)(ws + 16308224);               // 320,000
        hipMemsetAsync(ws, 0, 10486784, stream);
        hipLaunchKernelGGL(k_hist_fb, dim3(4096), dim3(256), 0, stream, cls, ctr, histF);
        hipLaunchKernelGGL(k_cutoff_fb, dim3(80), dim3(256), 0, stream, histF, bcutF);
        hipLaunchKernelGGL(k_compact_fb, dim3(4096), dim3(256), 0, stream, cls, ctr, bcutF, cntF, compactF);
        hipLaunchKernelGGL(k_select, dim3(80), dim3(1024), 0, stream, cntF, compactF, poolF);
        hipLaunchKernelGGL(k_merge, dim3(NB), dim3(1024), 0, stream, poolF, cntF, sortedF);
        hipLaunchKernelGGL(k_decode, dim3((NB * MM + 255) / 256), dim3(256), 0, stream,
                           sortedF, reg, locs, boxesF, scoresF, clsF, validF);
        hipLaunchKernelGGL(k_nms, dim3(NB), dim3(1024), 0, stream,
                           boxesF, scoresF, clsF, validF, (float*)d_out);
    }
}